// Round 10
// baseline (206.020 us; speedup 1.0000x reference)
//
#include <hip/hip_runtime.h>
#include <hip/hip_bf16.h>
#include <string.h>

// MHA B=2,S=2048,D=1024,H=16,Hd=64. Inputs fp32, output fp32.
// R26 (resubmit; R9 bench was a GPU-acquisition infra failure, kernel
// never ran). GEMM latency attack: (a) prep_x restored (R25's inline fp32
// staging re-converted X 24x -- FETCH 70MB, gemm_qkv_z 57us). (b) both
// GEMMs get the attn-proven dbuf+reg-prefetch structure: BK=32, double-
// buffered LDS, loads issued at iter top / written after compute,
// 1 barrier/iter. qkv LDS 36.9KB keeps 3 blocks/CU; out LDS 27.6KB,
// 2 blocks/CU. attn (R24 split-K, 52.3us) unchanged.

#define DM 1024
#define S_LEN 2048
#define NH 16
#define HD 64

using u16 = unsigned short;
using u32 = unsigned int;

typedef short bf16x8 __attribute__((ext_vector_type(8)));
typedef float f32x4  __attribute__((ext_vector_type(4)));
typedef float f32x16 __attribute__((ext_vector_type(16)));
typedef unsigned int u32x2 __attribute__((ext_vector_type(2)));

__device__ __forceinline__ u16 f2bf(float f) {
    u32 i = __float_as_uint(f);
    u32 r = i + 0x7fffu + ((i >> 16) & 1u);  // RNE
    return (u16)(r >> 16);
}
__device__ __forceinline__ u32 pk_bf16(float a, float b) {  // low16=a, high16=b (RNE)
    __hip_bfloat162 h = __float22bfloat162_rn(float2{a, b});
    u32 r; memcpy(&r, &h, 4);
    return r;
}

// ---- prep: x fp32 -> bf16 ----
__global__ __launch_bounds__(256) void prep_x(const float* __restrict__ X, u16* __restrict__ out) {
    int i = (blockIdx.x * 256 + threadIdx.x) * 4;
    float4 v = *(const float4*)(X + i);
    *(uint2*)(out + i) = make_uint2(pk_bf16(v.x, v.y), pk_bf16(v.z, v.w));
}

// ---- prep: W fp32 [K][N] -> W^T bf16 [N][K] ----
__global__ __launch_bounds__(256) void prep_wt3(
    const float* __restrict__ W0, const float* __restrict__ W1, const float* __restrict__ W2,
    u16* __restrict__ T0, u16* __restrict__ T1, u16* __restrict__ T2)
{
    __shared__ u16 tile[64][72];
    const float* W = (blockIdx.z == 0) ? W0 : (blockIdx.z == 1) ? W1 : W2;
    u16* WT        = (blockIdx.z == 0) ? T0 : (blockIdx.z == 1) ? T1 : T2;
    const int t = threadIdx.x;
    const int n0 = blockIdx.x * 64, k0 = blockIdx.y * 64;
    #pragma unroll
    for (int it = 0; it < 4; it++) {
        int k = it * 16 + (t >> 4);
        int n = (t & 15) * 4;
        float4 v = *(const float4*)(W + (size_t)(k0 + k) * DM + n0 + n);
        tile[n + 0][k] = f2bf(v.x);
        tile[n + 1][k] = f2bf(v.y);
        tile[n + 2][k] = f2bf(v.z);
        tile[n + 3][k] = f2bf(v.w);
    }
    __syncthreads();
    int n = t >> 2, kg = (t & 3) * 16;
    uint4 a = *(const uint4*)&tile[n][kg];
    uint4 b = *(const uint4*)&tile[n][kg + 8];
    *(uint4*)(WT + (size_t)(n0 + n) * DM + k0 + kg)     = a;
    *(uint4*)(WT + (size_t)(n0 + n) * DM + k0 + kg + 8) = b;
}

__global__ __launch_bounds__(256) void prep_wt1(const float* __restrict__ W, u16* __restrict__ WT) {
    __shared__ u16 tile[64][72];
    const int t = threadIdx.x;
    const int n0 = blockIdx.x * 64, k0 = blockIdx.y * 64;
    #pragma unroll
    for (int it = 0; it < 4; it++) {
        int k = it * 16 + (t >> 4);
        int n = (t & 15) * 4;
        float4 v = *(const float4*)(W + (size_t)(k0 + k) * DM + n0 + n);
        tile[n + 0][k] = f2bf(v.x);
        tile[n + 1][k] = f2bf(v.y);
        tile[n + 2][k] = f2bf(v.z);
        tile[n + 3][k] = f2bf(v.w);
    }
    __syncthreads();
    int n = t >> 2, kg = (t & 3) * 16;
    uint4 a = *(const uint4*)&tile[n][kg];
    uint4 b = *(const uint4*)&tile[n][kg + 8];
    *(uint4*)(WT + (size_t)(n0 + n) * DM + k0 + kg)     = a;
    *(uint4*)(WT + (size_t)(n0 + n) * DM + k0 + kg + 8) = b;
}

// ---- QKV projection, z-split: blockIdx.z selects Q/K/V. 128x128 tile,
// ---- BK=32, dbuf LDS + reg prefetch, 1 barrier/iter, 3 blocks/CU. ----
__global__ __launch_bounds__(256, 3) void gemm_qkv_z(
    const u16* __restrict__ WQT, const u16* __restrict__ WKT, const u16* __restrict__ WVT,
    const u16* __restrict__ X,
    const float* __restrict__ bq, const float* __restrict__ bk, const float* __restrict__ bv,
    u16* __restrict__ outQ, u16* __restrict__ outK, u16* __restrict__ outVT)
{
    __shared__ u16 Ws[2][128][36];
    __shared__ u16 Xs[2][128][36];

    const int z = blockIdx.z;
    const u16* WT = (z == 0) ? WQT : (z == 1) ? WKT : WVT;

    const int t = threadIdx.x;
    const int w = t >> 6, lane = t & 63, quad = lane >> 4, l16 = lane & 15;
    const int Mb0 = blockIdx.x * 128;
    const int Nb0 = blockIdx.y * 128;
    const int mloc = (w & 1) * 64, nloc = (w >> 1) * 64;

    f32x4 acc[4][4];
    #pragma unroll
    for (int i = 0; i < 4; i++)
        #pragma unroll
        for (int j = 0; j < 4; j++) acc[i][j] = (f32x4){0.f, 0.f, 0.f, 0.f};

    const int sr = t >> 2;           // 0..63
    const int sc8 = (t & 3) * 8;     // u16 col 0/8/16/24

    // prologue: k-step 0 -> buf 0
    #pragma unroll
    for (int i = 0; i < 2; i++) {
        int r = i * 64 + sr;
        *(uint4*)&Ws[0][r][sc8] = *(const uint4*)(WT + (size_t)(Mb0 + r) * DM + sc8);
        *(uint4*)&Xs[0][r][sc8] = *(const uint4*)(X  + (size_t)(Nb0 + r) * DM + sc8);
    }
    __syncthreads();

    for (int kt = 0; kt < 32; kt++) {
        const int cur = kt & 1;
        uint4 wr[2], xr[2];
        if (kt < 31) {
            const int k0 = (kt + 1) * 32;
            #pragma unroll
            for (int i = 0; i < 2; i++) {
                int r = i * 64 + sr;
                wr[i] = *(const uint4*)(WT + (size_t)(Mb0 + r) * DM + k0 + sc8);
                xr[i] = *(const uint4*)(X  + (size_t)(Nb0 + r) * DM + k0 + sc8);
            }
        }

        const int kk = quad * 8;
        bf16x8 af[4], bf[4];
        #pragma unroll
        for (int mt = 0; mt < 4; mt++)
            af[mt] = *(const bf16x8*)&Ws[cur][mloc + mt * 16 + l16][kk];
        #pragma unroll
        for (int nt = 0; nt < 4; nt++)
            bf[nt] = *(const bf16x8*)&Xs[cur][nloc + nt * 16 + l16][kk];
        #pragma unroll
        for (int mt = 0; mt < 4; mt++)
            #pragma unroll
            for (int nt = 0; nt < 4; nt++)
                acc[mt][nt] = __builtin_amdgcn_mfma_f32_16x16x32_bf16(af[mt], bf[nt], acc[mt][nt], 0, 0, 0);

        if (kt < 31) {
            #pragma unroll
            for (int i = 0; i < 2; i++) {
                int r = i * 64 + sr;
                *(uint4*)&Ws[cur ^ 1][r][sc8] = wr[i];
                *(uint4*)&Xs[cur ^ 1][r][sc8] = xr[i];
            }
        }
        __syncthreads();
    }

    const float QS = 0.18033688f;  // 0.125 * log2(e): attn uses raw v_exp (2^x)
    if (z <= 1) {
        u16* outP = (z == 0) ? outQ : outK;
        const float* bias = (z == 0) ? bq : bk;
        const float scale = (z == 0) ? QS : 1.0f;
        #pragma unroll
        for (int mt = 0; mt < 4; mt++) {
            int nf0 = Mb0 + mloc + mt * 16 + quad * 4;
            int hh = nf0 >> 6, hd = nf0 & 63;
            float4 bb = *(const float4*)(bias + nf0);
            #pragma unroll
            for (int nt = 0; nt < 4; nt++) {
                int m = Nb0 + nloc + nt * 16 + l16;
                int b = m >> 11, s = m & 2047;
                size_t idx = (size_t)(b * NH + hh) * 131072 + (size_t)s * 64 + hd;
                *(uint2*)(outP + idx) = make_uint2(
                    pk_bf16((acc[mt][nt][0] + bb.x) * scale, (acc[mt][nt][1] + bb.y) * scale),
                    pk_bf16((acc[mt][nt][2] + bb.z) * scale, (acc[mt][nt][3] + bb.w) * scale));
            }
        }
    } else {
        #pragma unroll
        for (int mt = 0; mt < 4; mt++) {
            #pragma unroll
            for (int r = 0; r < 4; r++) {
                int nf = Mb0 + mloc + mt * 16 + quad * 4 + r;
                int hh = nf >> 6, hd = nf & 63;
                float bb = bv[nf];
                #pragma unroll
                for (int nt = 0; nt < 4; nt++) {
                    int m = Nb0 + nloc + nt * 16 + l16;
                    int b = m >> 11, s = m & 2047;
                    outVT[(size_t)(b * NH + hh) * 131072 + (size_t)hd * S_LEN + s]
                        = f2bf(acc[mt][nt][r] + bb);
                }
            }
        }
    }
}

// ---- out GEMM: 64x128 tile, BK=32, dbuf LDS + reg prefetch,
// ---- 1 barrier/iter, 2 blocks/CU. ----
__global__ __launch_bounds__(256) void gemm_out(
    const u16* __restrict__ A, const u16* __restrict__ B,
    const float* __restrict__ bias, float* __restrict__ of32)
{
    __shared__ u16 As[2][64][36];
    __shared__ u16 Bs[2][128][36];

    const int t = threadIdx.x;
    const int w = t >> 6, lane = t & 63, quad = lane >> 4, l16 = lane & 15;
    const int Mb0 = blockIdx.x * 64;
    const int Nb0 = blockIdx.y * 128;
    const int Mb = Mb0 + (w & 1) * 32;
    const int Nb = Nb0 + (w >> 1) * 64;
    const int mloc = (w & 1) * 32, nloc = (w >> 1) * 64;

    f32x4 acc[2][4];
    #pragma unroll
    for (int i = 0; i < 2; i++)
        #pragma unroll
        for (int j = 0; j < 4; j++) acc[i][j] = (f32x4){0.f, 0.f, 0.f, 0.f};

    const int sr = t >> 2;           // 0..63
    const int sc8 = (t & 3) * 8;     // u16 col

    // prologue: k-step 0 (head 0, cols 0..31) -> buf 0
    *(uint4*)&As[0][sr][sc8] = *(const uint4*)(A + (size_t)(Mb0 + sr) * DM + sc8);
    #pragma unroll
    for (int i = 0; i < 2; i++) {
        int r = i * 64 + sr;
        int m = Nb0 + r;
        int b = m >> 11, s = m & 2047;
        *(uint4*)&Bs[0][r][sc8] =
            *(const uint4*)(B + (size_t)(b * NH + 0) * 131072 + (size_t)s * 64 + sc8);
    }
    __syncthreads();

    for (int kt = 0; kt < 32; kt++) {
        const int cur = kt & 1;
        uint4 ar, br[2];
        if (kt < 31) {
            const int kn = kt + 1;
            const int k0 = kn * 32;
            const int hn = kn >> 1, cn = (kn & 1) * 32;
            ar = *(const uint4*)(A + (size_t)(Mb0 + sr) * DM + k0 + sc8);
            #pragma unroll
            for (int i = 0; i < 2; i++) {
                int r = i * 64 + sr;
                int m = Nb0 + r;
                int b = m >> 11, s = m & 2047;
                br[i] = *(const uint4*)(B + (size_t)(b * NH + hn) * 131072 + (size_t)s * 64 + cn + sc8);
            }
        }

        const int kk = quad * 8;
        bf16x8 a0 = *(const bf16x8*)&As[cur][mloc + l16][kk];
        bf16x8 a1 = *(const bf16x8*)&As[cur][mloc + 16 + l16][kk];
        #pragma unroll
        for (int nt = 0; nt < 4; nt++) {
            bf16x8 bf = *(const bf16x8*)&Bs[cur][nloc + nt * 16 + l16][kk];
            acc[0][nt] = __builtin_amdgcn_mfma_f32_16x16x32_bf16(a0, bf, acc[0][nt], 0, 0, 0);
            acc[1][nt] = __builtin_amdgcn_mfma_f32_16x16x32_bf16(a1, bf, acc[1][nt], 0, 0, 0);
        }

        if (kt < 31) {
            *(uint4*)&As[cur ^ 1][sr][sc8] = ar;
            #pragma unroll
            for (int i = 0; i < 2; i++) {
                int r = i * 64 + sr;
                *(uint4*)&Bs[cur ^ 1][r][sc8] = br[i];
            }
        }
        __syncthreads();
    }

    #pragma unroll
    for (int mt = 0; mt < 2; mt++) {
        int nf0 = Mb + mt * 16 + quad * 4;
        float4 bvv = *(const float4*)(bias + nf0);
        #pragma unroll
        for (int nt = 0; nt < 4; nt++) {
            int m = Nb + nt * 16 + l16;
            float4 o;
            o.x = acc[mt][nt][0] + bvv.x; o.y = acc[mt][nt][1] + bvv.y;
            o.z = acc[mt][nt][2] + bvv.z; o.w = acc[mt][nt][3] + bvv.w;
            *(float4*)(of32 + (size_t)m * DM + nf0) = o;
        }
    }
}

// ---- attention: in-block split-K (R24, unchanged). ----
__global__ __launch_bounds__(512, 4) void attn_mfma(
    const u16* __restrict__ Q, const u16* __restrict__ K, const u16* __restrict__ VT,
    u16* __restrict__ O)
{
    __shared__ __align__(64) u16 smem[2][2][2][64][72];

    const int t = threadIdx.x;
    const int w = t >> 6, lane = t & 63;
    const int wq = w & 3, half = w >> 2;
    const int l32 = lane & 31, h = lane >> 5;
    const int bh = blockIdx.y;
    const int q0 = blockIdx.x * 128;
    const size_t base = (size_t)bh * 131072;

    const int qrow = q0 + wq * 32 + l32;
    bf16x8 qf[4];
    #pragma unroll
    for (int ks = 0; ks < 4; ks++)
        qf[ks] = *(const bf16x8*)(Q + base + (size_t)qrow * 64 + ks * 16 + h * 8);

    const short onebf = (short)0x3F80;
    const bf16x8 ones = {onebf, onebf, onebf, onebf, onebf, onebf, onebf, onebf};

    f32x16 o[2], lacc;
    #pragma unroll
    for (int ht = 0; ht < 2; ht++)
        #pragma unroll
        for (int i = 0; i < 16; i++) o[ht][i] = 0.f;
    #pragma unroll
    for (int i = 0; i < 16; i++) lacc[i] = 0.f;

    const int sr = t >> 3;            // 0..63
    const int sc8 = (t & 7) * 8;      // u16 col
    const u16* Kg = K + base;
    const u16* Vg = VT + base;

    *(uint4*)&smem[0][0][0][sr][sc8] = *(const uint4*)(Kg + (size_t)sr * 64 + sc8);
    *(uint4*)&smem[0][1][0][sr][sc8] = *(const uint4*)(Kg + (size_t)(16 * 64 + sr) * 64 + sc8);
    *(uint4*)&smem[1][0][0][sr][sc8] = *(const uint4*)(Vg + (size_t)sr * S_LEN + sc8);
    *(uint4*)&smem[1][1][0][sr][sc8] = *(const uint4*)(Vg + (size_t)sr * S_LEN + 16 * 64 + sc8);
    __syncthreads();

    for (int it = 0; it < 16; it++) {
        const int cur = it & 1;
        uint4 kra, krb, vra, vrb;
        if (it < 15) {
            kra = *(const uint4*)(Kg + (size_t)((it + 1) * 64 + sr) * 64 + sc8);
            krb = *(const uint4*)(Kg + (size_t)((it + 17) * 64 + sr) * 64 + sc8);
            vra = *(const uint4*)(Vg + (size_t)sr * S_LEN + (it + 1) * 64 + sc8);
            vrb = *(const uint4*)(Vg + (size_t)sr * S_LEN + (it + 17) * 64 + sc8);
        }

        const u16 (*Ksc)[72] = smem[0][half][cur];
        const u16 (*Vsc)[72] = smem[1][half][cur];

        #pragma unroll
        for (int kh = 0; kh < 2; kh++) {
            f32x16 s;
            #pragma unroll
            for (int i = 0; i < 16; i++) s[i] = 0.f;
            #pragma unroll
            for (int ks = 0; ks < 4; ks++) {
                bf16x8 kf = *(const bf16x8*)&Ksc[kh * 32 + l32][ks * 16 + h * 8];
                s = __builtin_amdgcn_mfma_f32_32x32x16_bf16(kf, qf[ks], s, 0, 0, 0);
            }
            float p[16];
            #pragma unroll
            for (int i = 0; i < 16; i++) p[i] = __builtin_amdgcn_exp2f(s[i]);
            u32 A0 = pk_bf16(p[0],  p[1]),  B0 = pk_bf16(p[2],  p[3]);
            u32 A1 = pk_bf16(p[4],  p[5]),  B1 = pk_bf16(p[6],  p[7]);
            u32 A2 = pk_bf16(p[8],  p[9]),  B2 = pk_bf16(p[10], p[11]);
            u32 A3 = pk_bf16(p[12], p[13]), B3 = pk_bf16(p[14], p[15]);
            u32x2 sA0 = __builtin_amdgcn_permlane32_swap(A0, A1, false, false);
            u32x2 sB0 = __builtin_amdgcn_permlane32_swap(B0, B1, false, false);
            u32x2 sA1 = __builtin_amdgcn_permlane32_swap(A2, A3, false, false);
            u32x2 sB1 = __builtin_amdgcn_permlane32_swap(B2, B3, false, false);
            union { bf16x8 v; u32 wd[4]; } fr0, fr1;
            fr0.wd[0] = sA0.x; fr0.wd[1] = sB0.x; fr0.wd[2] = sA0.y; fr0.wd[3] = sB0.y;
            fr1.wd[0] = sA1.x; fr1.wd[1] = sB1.x; fr1.wd[2] = sA1.y; fr1.wd[3] = sB1.y;

            lacc = __builtin_amdgcn_mfma_f32_32x32x16_bf16(fr0.v, ones, lacc, 0, 0, 0);
            lacc = __builtin_amdgcn_mfma_f32_32x32x16_bf16(fr1.v, ones, lacc, 0, 0, 0);

            #pragma unroll
            for (int ht = 0; ht < 2; ht++) {
                bf16x8 vf0 = *(const bf16x8*)&Vsc[ht * 32 + l32][kh * 32 + h * 8];
                o[ht] = __builtin_amdgcn_mfma_f32_32x32x16_bf16(fr0.v, vf0, o[ht], 0, 0, 0);
                bf16x8 vf1 = *(const bf16x8*)&Vsc[ht * 32 + l32][kh * 32 + 16 + h * 8];
                o[ht] = __builtin_amdgcn_mfma_f32_32x32x16_bf16(fr1.v, vf1, o[ht], 0, 0, 0);
            }
        }

        if (it < 15) {
            *(uint4*)&smem[0][0][cur ^ 1][sr][sc8] = kra;
            *(uint4*)&smem[0][1][cur ^ 1][sr][sc8] = krb;
            *(uint4*)&smem[1][0][cur ^ 1][sr][sc8] = vra;
            *(uint4*)&smem[1][1][cur ^ 1][sr][sc8] = vrb;
        }
        __syncthreads();
    }

    float* red = (float*)&smem[0][0][0][0][0];
    if (half) {
        #pragma unroll
        for (int i = 0; i < 16; i++) {
            red[((0 + wq) * 16 + i) * 64 + lane] = o[0][i];
            red[((4 + wq) * 16 + i) * 64 + lane] = o[1][i];
            red[((8 + wq) * 16 + i) * 64 + lane] = lacc[i];
        }
    }
    __syncthreads();
    if (!half) {
        #pragma unroll
        for (int i = 0; i < 16; i++) {
            o[0][i] += red[((0 + wq) * 16 + i) * 64 + lane];
            o[1][i] += red[((4 + wq) * 16 + i) * 64 + lane];
            lacc[i] += red[((8 + wq) * 16 + i) * 64 + lane];
        }
        float inv[16];
        #pragma unroll
        for (int r = 0; r < 16; r++) inv[r] = 1.0f / lacc[r];
        #pragma unroll
        for (int ht = 0; ht < 2; ht++)
            #pragma unroll
            for (int r = 0; r < 16; r++) {
                int q = q0 + wq * 32 + (r & 3) + 8 * (r >> 2) + 4 * h;
                O[base + (size_t)q * 64 + ht * 32 + l32] = f2bf(o[ht][r] * inv[r]);
            }
    }
}

extern "C" void kernel_launch(void* const* d_in, const int* in_sizes, int n_in,
                              void* d_out, int out_size, void* d_ws, size_t ws_size,
                              hipStream_t stream) {
    const float* x  = (const float*)d_in[0];
    const float* Wq = (const float*)d_in[1];
    const float* bq = (const float*)d_in[2];
    const float* Wk = (const float*)d_in[3];
    const float* bk = (const float*)d_in[4];
    const float* Wv = (const float*)d_in[5];
    const float* bv = (const float*)d_in[6];
    const float* Wo = (const float*)d_in[7];
    const float* bo = (const float*)d_in[8];
    float* out = (float*)d_out;

    // d_out as scratch during prep+proj (dead until final GEMM)
    u16* xbf = (u16*)d_out;
    u16* wqt = xbf + 4194304;
    u16* wkt = wqt + 1048576;
    u16* wvt = wkt + 1048576;

    u16* qws  = (u16*)d_ws;               // Q, later attnout (head layout)
    u16* kws  = qws + 4194304;            // K head layout; later Wo^T
    u16* vtws = kws + 4194304;            // V^T [bh][hd][s]
    u16* wot  = kws;

    prep_x<<<4096, 256, 0, stream>>>(x, xbf);
    prep_wt3<<<dim3(16, 16, 3), 256, 0, stream>>>(Wq, Wk, Wv, wqt, wkt, wvt);

    gemm_qkv_z<<<dim3(8, 32, 3), 256, 0, stream>>>(wqt, wkt, wvt, xbf, bq, bk, bv,
                                                   qws, kws, vtws);

    attn_mfma<<<dim3(16, 32), 512, 0, stream>>>(qws, kws, vtws, qws);

    prep_wt1<<<dim3(16, 16), 256, 0, stream>>>(Wo, wot);
    gemm_out<<<dim3(16, 32), 256, 0, stream>>>(wot, qws, bo, out);
}

// Round 13
// 200.132 us; speedup vs baseline: 1.0294x; 1.0294x over previous
//
#include <hip/hip_runtime.h>
#include <hip/hip_bf16.h>
#include <string.h>

// MHA B=2,S=2048,D=1024,H=16,Hd=64. Inputs fp32, output fp32.
// R27 (3rd resubmit; R10/R11/R12 benches were GPU-acquisition infra
// failures, kernel never ran). GEMMs revert to R23 shape (128-row tiles,
// BK=64, 2 barriers/step -- R26's BK=32 dbuf regressed +8us) and stage via
// global_load_lds width=16 (m93->m97 ladder step, +69% documented):
// linear LDS [rows][64], each wave-inst = 8 contiguous rows (64 lanes x
// 16B), no VGPR round-trip, no ds_writes. Known cost: 16-way bank
// conflict on fragment ds_read (linear LDS) -- m97 precedent says staging
// win dominates. attn (R24 split-K, ~52.3us) and preps unchanged.

#define DM 1024
#define S_LEN 2048
#define NH 16
#define HD 64

using u16 = unsigned short;
using u32 = unsigned int;

typedef short bf16x8 __attribute__((ext_vector_type(8)));
typedef float f32x4  __attribute__((ext_vector_type(4)));
typedef float f32x16 __attribute__((ext_vector_type(16)));
typedef unsigned int u32x2 __attribute__((ext_vector_type(2)));

__device__ __forceinline__ u16 f2bf(float f) {
    u32 i = __float_as_uint(f);
    u32 r = i + 0x7fffu + ((i >> 16) & 1u);  // RNE
    return (u16)(r >> 16);
}
__device__ __forceinline__ u32 pk_bf16(float a, float b) {  // low16=a, high16=b (RNE)
    __hip_bfloat162 h = __float22bfloat162_rn(float2{a, b});
    u32 r; memcpy(&r, &h, 4);
    return r;
}

// async global->LDS, 16B per lane; lds dest = wave-uniform base + lane*16
__device__ __forceinline__ void gload16(const u16* g, u16* l) {
    __builtin_amdgcn_global_load_lds(
        (const __attribute__((address_space(1))) void*)g,
        (__attribute__((address_space(3))) void*)l,
        16, 0, 0);
}

// ---- prep: x fp32 -> bf16 ----
__global__ __launch_bounds__(256) void prep_x(const float* __restrict__ X, u16* __restrict__ out) {
    int i = (blockIdx.x * 256 + threadIdx.x) * 4;
    float4 v = *(const float4*)(X + i);
    *(uint2*)(out + i) = make_uint2(pk_bf16(v.x, v.y), pk_bf16(v.z, v.w));
}

// ---- prep: W fp32 [K][N] -> W^T bf16 [N][K] ----
__global__ __launch_bounds__(256) void prep_wt3(
    const float* __restrict__ W0, const float* __restrict__ W1, const float* __restrict__ W2,
    u16* __restrict__ T0, u16* __restrict__ T1, u16* __restrict__ T2)
{
    __shared__ u16 tile[64][72];
    const float* W = (blockIdx.z == 0) ? W0 : (blockIdx.z == 1) ? W1 : W2;
    u16* WT        = (blockIdx.z == 0) ? T0 : (blockIdx.z == 1) ? T1 : T2;
    const int t = threadIdx.x;
    const int n0 = blockIdx.x * 64, k0 = blockIdx.y * 64;
    #pragma unroll
    for (int it = 0; it < 4; it++) {
        int k = it * 16 + (t >> 4);
        int n = (t & 15) * 4;
        float4 v = *(const float4*)(W + (size_t)(k0 + k) * DM + n0 + n);
        tile[n + 0][k] = f2bf(v.x);
        tile[n + 1][k] = f2bf(v.y);
        tile[n + 2][k] = f2bf(v.z);
        tile[n + 3][k] = f2bf(v.w);
    }
    __syncthreads();
    int n = t >> 2, kg = (t & 3) * 16;
    uint4 a = *(const uint4*)&tile[n][kg];
    uint4 b = *(const uint4*)&tile[n][kg + 8];
    *(uint4*)(WT + (size_t)(n0 + n) * DM + k0 + kg)     = a;
    *(uint4*)(WT + (size_t)(n0 + n) * DM + k0 + kg + 8) = b;
}

__global__ __launch_bounds__(256) void prep_wt1(const float* __restrict__ W, u16* __restrict__ WT) {
    __shared__ u16 tile[64][72];
    const int t = threadIdx.x;
    const int n0 = blockIdx.x * 64, k0 = blockIdx.y * 64;
    #pragma unroll
    for (int it = 0; it < 4; it++) {
        int k = it * 16 + (t >> 4);
        int n = (t & 15) * 4;
        float4 v = *(const float4*)(W + (size_t)(k0 + k) * DM + n0 + n);
        tile[n + 0][k] = f2bf(v.x);
        tile[n + 1][k] = f2bf(v.y);
        tile[n + 2][k] = f2bf(v.z);
        tile[n + 3][k] = f2bf(v.w);
    }
    __syncthreads();
    int n = t >> 2, kg = (t & 3) * 16;
    uint4 a = *(const uint4*)&tile[n][kg];
    uint4 b = *(const uint4*)&tile[n][kg + 8];
    *(uint4*)(WT + (size_t)(n0 + n) * DM + k0 + kg)     = a;
    *(uint4*)(WT + (size_t)(n0 + n) * DM + k0 + kg + 8) = b;
}

// ---- QKV projection, z-split. 128x128 tile, BK=64, global_load_lds
// ---- staging into linear LDS, 2 barriers/step, 3 blocks/CU. ----
__global__ __launch_bounds__(256, 3) void gemm_qkv_z(
    const u16* __restrict__ WQT, const u16* __restrict__ WKT, const u16* __restrict__ WVT,
    const u16* __restrict__ X,
    const float* __restrict__ bq, const float* __restrict__ bk, const float* __restrict__ bv,
    u16* __restrict__ outQ, u16* __restrict__ outK, u16* __restrict__ outVT)
{
    __shared__ u16 Ws[128][64];
    __shared__ u16 Xs[128][64];

    const int z = blockIdx.z;
    const u16* WT = (z == 0) ? WQT : (z == 1) ? WKT : WVT;

    const int t = threadIdx.x;
    const int w = t >> 6, lane = t & 63, quad = lane >> 4, l16 = lane & 15;
    const int Mb0 = blockIdx.x * 128;
    const int Nb0 = blockIdx.y * 128;
    const int mloc = (w & 1) * 64, nloc = (w >> 1) * 64;

    f32x4 acc[4][4];
    #pragma unroll
    for (int i = 0; i < 4; i++)
        #pragma unroll
        for (int j = 0; j < 4; j++) acc[i][j] = (f32x4){0.f, 0.f, 0.f, 0.f};

    // staging geometry: wave-inst i covers rows i*32 + w*8 .. +7
    const int srow = lane >> 3;          // 0..7
    const int scol = (lane & 7) * 8;     // u16 col
    const u16* wg = WT + (size_t)(Mb0 + w * 8 + srow) * DM + scol;
    const u16* xg = X  + (size_t)(Nb0 + w * 8 + srow) * DM + scol;
    u16* wl = &Ws[w * 8][0];             // wave-uniform LDS bases
    u16* xl = &Xs[w * 8][0];

    for (int k0 = 0; k0 < DM; k0 += 64) {
        __syncthreads();
        #pragma unroll
        for (int i = 0; i < 4; i++) {
            gload16(wg + (size_t)(i * 32) * DM + k0, wl + i * 32 * 64);
            gload16(xg + (size_t)(i * 32) * DM + k0, xl + i * 32 * 64);
        }
        __syncthreads();   // drains vmcnt(0): LDS tiles ready

        #pragma unroll
        for (int ks = 0; ks < 2; ks++) {
            const int kk = ks * 32 + quad * 8;
            bf16x8 af[4], bf[4];
            #pragma unroll
            for (int mt = 0; mt < 4; mt++)
                af[mt] = *(const bf16x8*)&Ws[mloc + mt * 16 + l16][kk];
            #pragma unroll
            for (int nt = 0; nt < 4; nt++)
                bf[nt] = *(const bf16x8*)&Xs[nloc + nt * 16 + l16][kk];
            #pragma unroll
            for (int mt = 0; mt < 4; mt++)
                #pragma unroll
                for (int nt = 0; nt < 4; nt++)
                    acc[mt][nt] = __builtin_amdgcn_mfma_f32_16x16x32_bf16(af[mt], bf[nt], acc[mt][nt], 0, 0, 0);
        }
    }

    const float QS = 0.18033688f;  // 0.125 * log2(e): attn uses raw v_exp (2^x)
    if (z <= 1) {
        u16* outP = (z == 0) ? outQ : outK;
        const float* bias = (z == 0) ? bq : bk;
        const float scale = (z == 0) ? QS : 1.0f;
        #pragma unroll
        for (int mt = 0; mt < 4; mt++) {
            int nf0 = Mb0 + mloc + mt * 16 + quad * 4;
            int hh = nf0 >> 6, hd = nf0 & 63;
            float4 bb = *(const float4*)(bias + nf0);
            #pragma unroll
            for (int nt = 0; nt < 4; nt++) {
                int m = Nb0 + nloc + nt * 16 + l16;
                int b = m >> 11, s = m & 2047;
                size_t idx = (size_t)(b * NH + hh) * 131072 + (size_t)s * 64 + hd;
                *(uint2*)(outP + idx) = make_uint2(
                    pk_bf16((acc[mt][nt][0] + bb.x) * scale, (acc[mt][nt][1] + bb.y) * scale),
                    pk_bf16((acc[mt][nt][2] + bb.z) * scale, (acc[mt][nt][3] + bb.w) * scale));
            }
        }
    } else {
        #pragma unroll
        for (int mt = 0; mt < 4; mt++) {
            #pragma unroll
            for (int r = 0; r < 4; r++) {
                int nf = Mb0 + mloc + mt * 16 + quad * 4 + r;
                int hh = nf >> 6, hd = nf & 63;
                float bb = bv[nf];
                #pragma unroll
                for (int nt = 0; nt < 4; nt++) {
                    int m = Nb0 + nloc + nt * 16 + l16;
                    int b = m >> 11, s = m & 2047;
                    outVT[(size_t)(b * NH + hh) * 131072 + (size_t)hd * S_LEN + s]
                        = f2bf(acc[mt][nt][r] + bb);
                }
            }
        }
    }
}

// ---- out GEMM: 64x128 tile, BK=64 (= one head/step), global_load_lds
// ---- staging into linear LDS, 2 barriers/step. ----
__global__ __launch_bounds__(256) void gemm_out(
    const u16* __restrict__ A, const u16* __restrict__ B,
    const float* __restrict__ bias, float* __restrict__ of32)
{
    __shared__ u16 As[64][64];
    __shared__ u16 Bs[128][64];

    const int t = threadIdx.x;
    const int w = t >> 6, lane = t & 63, quad = lane >> 4, l16 = lane & 15;
    const int Mb0 = blockIdx.x * 64;
    const int Nb0 = blockIdx.y * 128;
    const int Mb = Mb0 + (w & 1) * 32;
    const int Nb = Nb0 + (w >> 1) * 64;
    const int mloc = (w & 1) * 32, nloc = (w >> 1) * 64;

    f32x4 acc[2][4];
    #pragma unroll
    for (int i = 0; i < 2; i++)
        #pragma unroll
        for (int j = 0; j < 4; j++) acc[i][j] = (f32x4){0.f, 0.f, 0.f, 0.f};

    const int srow = lane >> 3;          // 0..7
    const int scol = (lane & 7) * 8;     // u16 col
    const u16* ag = A + (size_t)(Mb0 + w * 8 + srow) * DM + scol;
    u16* al = &As[w * 8][0];
    const int bb = Nb0 >> 11;            // batch (tile fits in one)
    const int s0 = (Nb0 & 2047) + w * 8 + srow;
    const u16* bg = B + (size_t)bb * NH * 131072 + (size_t)s0 * 64 + scol;
    u16* bl = &Bs[w * 8][0];

    for (int kt = 0; kt < 16; kt++) {    // BK=64 = head kt
        const int k0 = kt * 64;
        __syncthreads();
        #pragma unroll
        for (int i = 0; i < 2; i++)
            gload16(ag + (size_t)(i * 32) * DM + k0, al + i * 32 * 64);
        #pragma unroll
        for (int i = 0; i < 4; i++)
            gload16(bg + (size_t)kt * 131072 + (size_t)(i * 32) * 64, bl + i * 32 * 64);
        __syncthreads();

        #pragma unroll
        for (int ks = 0; ks < 2; ks++) {
            const int kk = ks * 32 + quad * 8;
            bf16x8 a0 = *(const bf16x8*)&As[mloc + l16][kk];
            bf16x8 a1 = *(const bf16x8*)&As[mloc + 16 + l16][kk];
            #pragma unroll
            for (int nt = 0; nt < 4; nt++) {
                bf16x8 bf = *(const bf16x8*)&Bs[nloc + nt * 16 + l16][kk];
                acc[0][nt] = __builtin_amdgcn_mfma_f32_16x16x32_bf16(a0, bf, acc[0][nt], 0, 0, 0);
                acc[1][nt] = __builtin_amdgcn_mfma_f32_16x16x32_bf16(a1, bf, acc[1][nt], 0, 0, 0);
            }
        }
    }

    #pragma unroll
    for (int mt = 0; mt < 2; mt++) {
        int nf0 = Mb + mt * 16 + quad * 4;
        float4 bvv = *(const float4*)(bias + nf0);
        #pragma unroll
        for (int nt = 0; nt < 4; nt++) {
            int m = Nb + nt * 16 + l16;
            float4 o;
            o.x = acc[mt][nt][0] + bvv.x; o.y = acc[mt][nt][1] + bvv.y;
            o.z = acc[mt][nt][2] + bvv.z; o.w = acc[mt][nt][3] + bvv.w;
            *(float4*)(of32 + (size_t)m * DM + nf0) = o;
        }
    }
}

// ---- attention: in-block split-K (R24, unchanged). ----
__global__ __launch_bounds__(512, 4) void attn_mfma(
    const u16* __restrict__ Q, const u16* __restrict__ K, const u16* __restrict__ VT,
    u16* __restrict__ O)
{
    __shared__ __align__(64) u16 smem[2][2][2][64][72];

    const int t = threadIdx.x;
    const int w = t >> 6, lane = t & 63;
    const int wq = w & 3, half = w >> 2;
    const int l32 = lane & 31, h = lane >> 5;
    const int bh = blockIdx.y;
    const int q0 = blockIdx.x * 128;
    const size_t base = (size_t)bh * 131072;

    const int qrow = q0 + wq * 32 + l32;
    bf16x8 qf[4];
    #pragma unroll
    for (int ks = 0; ks < 4; ks++)
        qf[ks] = *(const bf16x8*)(Q + base + (size_t)qrow * 64 + ks * 16 + h * 8);

    const short onebf = (short)0x3F80;
    const bf16x8 ones = {onebf, onebf, onebf, onebf, onebf, onebf, onebf, onebf};

    f32x16 o[2], lacc;
    #pragma unroll
    for (int ht = 0; ht < 2; ht++)
        #pragma unroll
        for (int i = 0; i < 16; i++) o[ht][i] = 0.f;
    #pragma unroll
    for (int i = 0; i < 16; i++) lacc[i] = 0.f;

    const int sr = t >> 3;            // 0..63
    const int sc8 = (t & 7) * 8;      // u16 col
    const u16* Kg = K + base;
    const u16* Vg = VT + base;

    *(uint4*)&smem[0][0][0][sr][sc8] = *(const uint4*)(Kg + (size_t)sr * 64 + sc8);
    *(uint4*)&smem[0][1][0][sr][sc8] = *(const uint4*)(Kg + (size_t)(16 * 64 + sr) * 64 + sc8);
    *(uint4*)&smem[1][0][0][sr][sc8] = *(const uint4*)(Vg + (size_t)sr * S_LEN + sc8);
    *(uint4*)&smem[1][1][0][sr][sc8] = *(const uint4*)(Vg + (size_t)sr * S_LEN + 16 * 64 + sc8);
    __syncthreads();

    for (int it = 0; it < 16; it++) {
        const int cur = it & 1;
        uint4 kra, krb, vra, vrb;
        if (it < 15) {
            kra = *(const uint4*)(Kg + (size_t)((it + 1) * 64 + sr) * 64 + sc8);
            krb = *(const uint4*)(Kg + (size_t)((it + 17) * 64 + sr) * 64 + sc8);
            vra = *(const uint4*)(Vg + (size_t)sr * S_LEN + (it + 1) * 64 + sc8);
            vrb = *(const uint4*)(Vg + (size_t)sr * S_LEN + (it + 17) * 64 + sc8);
        }

        const u16 (*Ksc)[72] = smem[0][half][cur];
        const u16 (*Vsc)[72] = smem[1][half][cur];

        #pragma unroll
        for (int kh = 0; kh < 2; kh++) {
            f32x16 s;
            #pragma unroll
            for (int i = 0; i < 16; i++) s[i] = 0.f;
            #pragma unroll
            for (int ks = 0; ks < 4; ks++) {
                bf16x8 kf = *(const bf16x8*)&Ksc[kh * 32 + l32][ks * 16 + h * 8];
                s = __builtin_amdgcn_mfma_f32_32x32x16_bf16(kf, qf[ks], s, 0, 0, 0);
            }
            float p[16];
            #pragma unroll
            for (int i = 0; i < 16; i++) p[i] = __builtin_amdgcn_exp2f(s[i]);
            u32 A0 = pk_bf16(p[0],  p[1]),  B0 = pk_bf16(p[2],  p[3]);
            u32 A1 = pk_bf16(p[4],  p[5]),  B1 = pk_bf16(p[6],  p[7]);
            u32 A2 = pk_bf16(p[8],  p[9]),  B2 = pk_bf16(p[10], p[11]);
            u32 A3 = pk_bf16(p[12], p[13]), B3 = pk_bf16(p[14], p[15]);
            u32x2 sA0 = __builtin_amdgcn_permlane32_swap(A0, A1, false, false);
            u32x2 sB0 = __builtin_amdgcn_permlane32_swap(B0, B1, false, false);
            u32x2 sA1 = __builtin_amdgcn_permlane32_swap(A2, A3, false, false);
            u32x2 sB1 = __builtin_amdgcn_permlane32_swap(B2, B3, false, false);
            union { bf16x8 v; u32 wd[4]; } fr0, fr1;
            fr0.wd[0] = sA0.x; fr0.wd[1] = sB0.x; fr0.wd[2] = sA0.y; fr0.wd[3] = sB0.y;
            fr1.wd[0] = sA1.x; fr1.wd[1] = sB1.x; fr1.wd[2] = sA1.y; fr1.wd[3] = sB1.y;

            lacc = __builtin_amdgcn_mfma_f32_32x32x16_bf16(fr0.v, ones, lacc, 0, 0, 0);
            lacc = __builtin_amdgcn_mfma_f32_32x32x16_bf16(fr1.v, ones, lacc, 0, 0, 0);

            #pragma unroll
            for (int ht = 0; ht < 2; ht++) {
                bf16x8 vf0 = *(const bf16x8*)&Vsc[ht * 32 + l32][kh * 32 + h * 8];
                o[ht] = __builtin_amdgcn_mfma_f32_32x32x16_bf16(fr0.v, vf0, o[ht], 0, 0, 0);
                bf16x8 vf1 = *(const bf16x8*)&Vsc[ht * 32 + l32][kh * 32 + 16 + h * 8];
                o[ht] = __builtin_amdgcn_mfma_f32_32x32x16_bf16(fr1.v, vf1, o[ht], 0, 0, 0);
            }
        }

        if (it < 15) {
            *(uint4*)&smem[0][0][cur ^ 1][sr][sc8] = kra;
            *(uint4*)&smem[0][1][cur ^ 1][sr][sc8] = krb;
            *(uint4*)&smem[1][0][cur ^ 1][sr][sc8] = vra;
            *(uint4*)&smem[1][1][cur ^ 1][sr][sc8] = vrb;
        }
        __syncthreads();
    }

    float* red = (float*)&smem[0][0][0][0][0];
    if (half) {
        #pragma unroll
        for (int i = 0; i < 16; i++) {
            red[((0 + wq) * 16 + i) * 64 + lane] = o[0][i];
            red[((4 + wq) * 16 + i) * 64 + lane] = o[1][i];
            red[((8 + wq) * 16 + i) * 64 + lane] = lacc[i];
        }
    }
    __syncthreads();
    if (!half) {
        #pragma unroll
        for (int i = 0; i < 16; i++) {
            o[0][i] += red[((0 + wq) * 16 + i) * 64 + lane];
            o[1][i] += red[((4 + wq) * 16 + i) * 64 + lane];
            lacc[i] += red[((8 + wq) * 16 + i) * 64 + lane];
        }
        float inv[16];
        #pragma unroll
        for (int r = 0; r < 16; r++) inv[r] = 1.0f / lacc[r];
        #pragma unroll
        for (int ht = 0; ht < 2; ht++)
            #pragma unroll
            for (int r = 0; r < 16; r++) {
                int q = q0 + wq * 32 + (r & 3) + 8 * (r >> 2) + 4 * h;
                O[base + (size_t)q * 64 + ht * 32 + l32] = f2bf(o[ht][r] * inv[r]);
            }
    }
}

extern "C" void kernel_launch(void* const* d_in, const int* in_sizes, int n_in,
                              void* d_out, int out_size, void* d_ws, size_t ws_size,
                              hipStream_t stream) {
    const float* x  = (const float*)d_in[0];
    const float* Wq = (const float*)d_in[1];
    const float* bq = (const float*)d_in[2];
    const float* Wk = (const float*)d_in[3];
    const float* bk = (const float*)d_in[4];
    const float* Wv = (const float*)d_in[5];
    const float* bv = (const float*)d_in[6];
    const float* Wo = (const float*)d_in[7];
    const float* bo = (const float*)d_in[8];
    float* out = (float*)d_out;

    // d_out as scratch during prep+proj (dead until final GEMM)
    u16* xbf = (u16*)d_out;
    u16* wqt = xbf + 4194304;
    u16* wkt = wqt + 1048576;
    u16* wvt = wkt + 1048576;

    u16* qws  = (u16*)d_ws;               // Q, later attnout (head layout)
    u16* kws  = qws + 4194304;            // K head layout; later Wo^T
    u16* vtws = kws + 4194304;            // V^T [bh][hd][s]
    u16* wot  = kws;

    prep_x<<<4096, 256, 0, stream>>>(x, xbf);
    prep_wt3<<<dim3(16, 16, 3), 256, 0, stream>>>(Wq, Wk, Wv, wqt, wkt, wvt);

    gemm_qkv_z<<<dim3(8, 32, 3), 256, 0, stream>>>(wqt, wkt, wvt, xbf, bq, bk, bv,
                                                   qws, kws, vtws);

    attn_mfma<<<dim3(16, 32), 512, 0, stream>>>(qws, kws, vtws, qws);

    prep_wt1<<<dim3(16, 16), 256, 0, stream>>>(Wo, wot);
    gemm_out<<<dim3(16, 32), 256, 0, stream>>>(wot, qws, bo, out);
}